// Round 19
// baseline (100.720 us; speedup 1.0000x reference)
//
#include <hip/hip_runtime.h>

// MaskedDenseMatMul: out[b,h,q,k] = (sum_d a[b,h,q,d]*b[b,h,k,d]) * mask[b,0,q,k]
// B=2 H=8 S=2048 D=64, fp32 in/out.  Memory-bound on the 256 MiB output write.
//
// R19 design — producer/consumer with 2x the storing waves:
//  R18 (granule 2x) was NULL -> stall scales with work = throughput ceiling,
//  not handshake overhead.  The fill kernel (6.9 TB/s) runs ~13 storing
//  waves/CU; R17/18 ran 8.  Here: 512-thread blocks, 8 waves = 4 producers
//  (32 cols each, <=64 VGPR) + 4 consumers; __launch_bounds__(512,8) ->
//  32 waves/CU = 4 blocks/CU -> 16 consumer (storing) waves per CU, 2x R17.
//   - producer: 2 loop-invariant B tiles (16 VGPR), depth-2 A+mask staging,
//     4 MFMA + select + publish per 16-row granule, lgkmcnt(0) + raw barrier
//   - consumer: 2 ds_read + 2 nt stores (4 rows x 128 cols) per granule;
//     vmcnt FIFO = stores only, never drained
//   - 1024 blocks = 16 col panels x 4 row quarters x 16 bh = exactly one
//     full-occupancy round; consecutive blocks = adjacent col panels
//  Abort criterion: >=74us -> C-wave count refuted, revert to R17.

typedef __attribute__((ext_vector_type(8))) short bf16x8;
typedef __attribute__((ext_vector_type(4))) float f32x4;
typedef __attribute__((ext_vector_type(2))) unsigned int u32x2;

static constexpr int S = 2048;
static constexpr int D = 64;
static constexpr size_t NELEM = (size_t)16 * S * D;   // elems per A/B input
static constexpr size_t NMASK = (size_t)2 * S * S;    // mask elems (B*S*S)
static constexpr int LR = 132;                        // LDS row stride (pad)

__device__ inline short f2bf(float f) {
    union { float f; unsigned u; } v; v.f = f;
    unsigned r = (v.u + 0x7FFFu + ((v.u >> 16) & 1u)) >> 16;
    return (short)r;
}

// ------------- fused pre-pass: cvt A (1024 blk), cvt B (1024), pack mask (4096)
__global__ __launch_bounds__(256) void prep_kernel(const float* __restrict__ a,
                                                   const float* __restrict__ b,
                                                   const float* __restrict__ m,
                                                   short* __restrict__ a16,
                                                   short* __restrict__ b16,
                                                   unsigned char* __restrict__ m8) {
    const int blk = blockIdx.x;
    if (blk < 2048) {
        const float* src = (blk < 1024) ? a : b;
        short* dst       = (blk < 1024) ? a16 : b16;
        size_t i = ((size_t)(blk & 1023) * 256 + threadIdx.x) * 8;
        f32x4 f0 = *(const f32x4*)(src + i);
        f32x4 f1 = *(const f32x4*)(src + i + 4);
        bf16x8 t;
        t[0] = f2bf(f0[0]); t[1] = f2bf(f0[1]); t[2] = f2bf(f0[2]); t[3] = f2bf(f0[3]);
        t[4] = f2bf(f1[0]); t[5] = f2bf(f1[1]); t[6] = f2bf(f1[2]); t[7] = f2bf(f1[3]);
        *(bf16x8*)(dst + i) = t;
    } else {
        size_t i = ((size_t)(blk - 2048) * 256 + threadIdx.x) * 8;
        f32x4 f0 = *(const f32x4*)(m + i);
        f32x4 f1 = *(const f32x4*)(m + i + 4);
        unsigned w0 = 0, w1 = 0;
        w0 |= (f0[0] != 0.f ? 1u : 0u);
        w0 |= (f0[1] != 0.f ? 1u : 0u) << 8;
        w0 |= (f0[2] != 0.f ? 1u : 0u) << 16;
        w0 |= (f0[3] != 0.f ? 1u : 0u) << 24;
        w1 |= (f1[0] != 0.f ? 1u : 0u);
        w1 |= (f1[1] != 0.f ? 1u : 0u) << 8;
        w1 |= (f1[2] != 0.f ? 1u : 0u) << 16;
        w1 |= (f1[3] != 0.f ? 1u : 0u) << 24;
        u32x2 w; w[0] = w0; w[1] = w1;
        *(u32x2*)(m8 + i) = w;
    }
}

// ------------- main kernel: 8-wave P/C (4 producers + 4 consumers) -----------
__global__ __launch_bounds__(512, 8) void masked_mm_pc8_kernel(
    const short* __restrict__ A16,
    const short* __restrict__ B16,
    const unsigned char* __restrict__ M8,
    float* __restrict__ O) {

    __shared__ float lds[2][16][LR];          // 16896 B double buffer

    const int lane = threadIdx.x & 63;
    const int w    = threadIdx.x >> 6;        // 0-3 producers; 4-7 consumers

    const int gw = blockIdx.x;                // 0..1023
    const int cp = gw & 15;                   // 16 col panels of 128
    const int rq = (gw >> 4) & 3;             // 4 row quarters of 512
    const int bh = gw >> 6;                   // 0..15
    const int bb = bh >> 3;

    const int c0 = cp * 128;
    const int r0 = rq * 512;

    const short* __restrict__ Bb = B16 + (size_t)bh * S * D;
    const unsigned char* __restrict__ Mb = M8 + (size_t)bb * S * S;
    float* __restrict__ Ob       = O + (size_t)bh * S * S;

    if (w < 4) {
        // ================= PRODUCER (global loads only) =================
        const short* __restrict__ Ab = A16 + (size_t)bh * S * D;
        const int rlane = lane & 15;          // MFMA operand row within 16
        const int kg    = lane >> 4;          // k-group 0..3
        const int wc0   = c0 + w * 32;        // this producer's 32 cols

        // loop-invariant B fragments: 2 tiles x (2 x K=32) = 16 VGPR
        bf16x8 bs0[2], bs1[2];
#pragma unroll
        for (int t = 0; t < 2; ++t) {
            const short* pb = Bb + (size_t)(wc0 + t * 16 + rlane) * D + kg * 8;
            bs0[t] = *(const bf16x8*)(pb);
            bs1[t] = *(const bf16x8*)(pb + 32);
        }

        const short*         pa0 = Ab + (size_t)(r0 + rlane) * D + kg * 8;
        const unsigned char* pm0 = Mb + (size_t)(r0 + rlane) * S + wc0 + kg * 4;

        // depth-2 register staging (A frags + mask words)
        bf16x8   sa0[2], sa1[2];
        unsigned smw[2][2];
#pragma unroll
        for (int n = 0; n < 2; ++n) {
            sa0[n] = *(const bf16x8*)(pa0 + (size_t)n * 16 * D);
            sa1[n] = *(const bf16x8*)(pa0 + (size_t)n * 16 * D + 32);
#pragma unroll
            for (int t = 0; t < 2; ++t)
                smw[n][t] = *(const unsigned*)(pm0 + (size_t)n * 16 * S + t * 16);
        }

#pragma unroll
        for (int n = 0; n < 32; ++n) {
            const int sl = n & 1;

            f32x4 acc[2];
#pragma unroll
            for (int t = 0; t < 2; ++t) {
                f32x4 z = {0.f, 0.f, 0.f, 0.f};
                z = __builtin_amdgcn_mfma_f32_16x16x32_bf16(bs0[t], sa0[sl], z, 0, 0, 0);
                z = __builtin_amdgcn_mfma_f32_16x16x32_bf16(bs1[t], sa1[sl], z, 0, 0, 0);
                acc[t] = z;
            }

            // mask select (producer applies mask so consumer is pure copy)
#pragma unroll
            for (int t = 0; t < 2; ++t) {
                const unsigned m = smw[sl][t];
                acc[t][0] = (m & 0x000000FFu) ? acc[t][0] : 0.f;
                acc[t][1] = (m & 0x0000FF00u) ? acc[t][1] : 0.f;
                acc[t][2] = (m & 0x00FF0000u) ? acc[t][2] : 0.f;
                acc[t][3] = (m & 0xFF000000u) ? acc[t][3] : 0.f;
            }

            // prefetch n+2 (pure loads; producer never stores to global)
            if (n + 2 < 32) {
                sa0[sl] = *(const bf16x8*)(pa0 + (size_t)(n + 2) * 16 * D);
                sa1[sl] = *(const bf16x8*)(pa0 + (size_t)(n + 2) * 16 * D + 32);
#pragma unroll
                for (int t = 0; t < 2; ++t)
                    smw[sl][t] = *(const unsigned*)(pm0 + (size_t)(n + 2) * 16 * S + t * 16);
            }

            // publish group n to the double buffer
#pragma unroll
            for (int t = 0; t < 2; ++t)
                *(f32x4*)&lds[n & 1][rlane][w * 32 + t * 16 + kg * 4] = acc[t];

            asm volatile("s_waitcnt lgkmcnt(0)" ::: "memory");
            __builtin_amdgcn_s_barrier();
        }
    } else {
        // ================= CONSUMER (global stores only) =================
        const int cw  = w - 4;                // 0..3 -> rows 4cw..4cw+3
        const int h2  = lane >> 5;            // row within pair
        const int c32 = lane & 31;            // col/4 within 128-col panel

#pragma unroll
        for (int n = 0; n < 32; ++n) {
            __builtin_amdgcn_s_barrier();
            asm volatile("" ::: "memory");    // no ds_read hoist above barrier

#pragma unroll
            for (int p = 0; p < 2; ++p) {
                const int rr = cw * 4 + 2 * p + h2;
                f32x4 v = *(const f32x4*)&lds[n & 1][rr][c32 * 4];
                __builtin_nontemporal_store(v,
                    (f32x4*)(Ob + (size_t)(r0 + n * 16 + rr) * S + c0 + c32 * 4));
            }
        }
    }
}

// ---------------- fallback (ws too small): inline conversion -----------------
__global__ __launch_bounds__(256) void masked_mm_f32_kernel(
    const float* __restrict__ A,
    const float* __restrict__ B,
    const float* __restrict__ M,
    float* __restrict__ O) {

    const int bh   = blockIdx.z;
    const int bb   = bh >> 3;
    const int lane = threadIdx.x & 63;
    const int w    = threadIdx.x >> 6;
    const int r0 = blockIdx.y * 64 + w * 16;
    const int c0 = blockIdx.x * 256;
    const int rlane = lane & 15;
    const int kg    = lane >> 4;

    const float* __restrict__ Ab = A + (size_t)bh * S * D;
    const float* __restrict__ Bb = B + (size_t)bh * S * D;
    const float* __restrict__ Mb = M + (size_t)bb * S * S;
    float* __restrict__ Ob       = O + (size_t)bh * S * S;

    const float* pa = Ab + (size_t)(r0 + rlane) * D + kg * 8;
    f32x4 fa0 = *(const f32x4*)pa, fa1 = *(const f32x4*)(pa + 4);
    f32x4 fa2 = *(const f32x4*)(pa + 32), fa3 = *(const f32x4*)(pa + 36);
    bf16x8 af0, af1;
    af0[0]=f2bf(fa0[0]); af0[1]=f2bf(fa0[1]); af0[2]=f2bf(fa0[2]); af0[3]=f2bf(fa0[3]);
    af0[4]=f2bf(fa1[0]); af0[5]=f2bf(fa1[1]); af0[6]=f2bf(fa1[2]); af0[7]=f2bf(fa1[3]);
    af1[0]=f2bf(fa2[0]); af1[1]=f2bf(fa2[1]); af1[2]=f2bf(fa2[2]); af1[3]=f2bf(fa2[3]);
    af1[4]=f2bf(fa3[0]); af1[5]=f2bf(fa3[1]); af1[6]=f2bf(fa3[2]); af1[7]=f2bf(fa3[3]);

    const size_t rowbase = (size_t)(r0 + rlane) * S + c0;

#pragma unroll
    for (int t = 0; t < 16; ++t) {
        const float* pb = Bb + (size_t)(c0 + t * 16 + rlane) * D + kg * 8;
        f32x4 g0 = *(const f32x4*)pb, g1 = *(const f32x4*)(pb + 4);
        f32x4 g2 = *(const f32x4*)(pb + 32), g3 = *(const f32x4*)(pb + 36);
        bf16x8 b0, b1;
        b0[0]=f2bf(g0[0]); b0[1]=f2bf(g0[1]); b0[2]=f2bf(g0[2]); b0[3]=f2bf(g0[3]);
        b0[4]=f2bf(g1[0]); b0[5]=f2bf(g1[1]); b0[6]=f2bf(g1[2]); b0[7]=f2bf(g1[3]);
        b1[0]=f2bf(g2[0]); b1[1]=f2bf(g2[1]); b1[2]=f2bf(g2[2]); b1[3]=f2bf(g2[3]);
        b1[4]=f2bf(g3[0]); b1[5]=f2bf(g3[1]); b1[6]=f2bf(g3[2]); b1[7]=f2bf(g3[3]);
        f32x4 z = {0.f, 0.f, 0.f, 0.f};
        z = __builtin_amdgcn_mfma_f32_16x16x32_bf16(b0, af0, z, 0, 0, 0);
        z = __builtin_amdgcn_mfma_f32_16x16x32_bf16(b1, af1, z, 0, 0, 0);
        f32x4 mkv = *(const f32x4*)(Mb + rowbase + t * 16 + kg * 4);
        z[0] *= mkv[0]; z[1] *= mkv[1]; z[2] *= mkv[2]; z[3] *= mkv[3];
        *(f32x4*)(Ob + rowbase + t * 16 + kg * 4) = z;
    }
}

extern "C" void kernel_launch(void* const* d_in, const int* in_sizes, int n_in,
                              void* d_out, int out_size, void* d_ws, size_t ws_size,
                              hipStream_t stream) {
    const float* a = (const float*)d_in[0];
    const float* b = (const float*)d_in[1];
    const float* m = (const float*)d_in[2];
    float* o = (float*)d_out;

    const size_t ws_need = 2 * NELEM * sizeof(short) + NMASK;  // 8.4 + 8.4 MB
    if (ws_size >= ws_need) {
        short* a16 = (short*)d_ws;
        short* b16 = a16 + NELEM;
        unsigned char* m8 = (unsigned char*)(b16 + NELEM);
        hipLaunchKernelGGL(prep_kernel, dim3(6144), dim3(256), 0, stream,
                           a, b, m, a16, b16, m8);
        // 1024 blocks x 512 threads = 16 col panels x 4 row quarters x 16 bh
        hipLaunchKernelGGL(masked_mm_pc8_kernel, dim3(1024), dim3(512), 0, stream,
                           a16, b16, m8, o);
    } else {
        dim3 grid(S / 256, S / 64, 16);
        hipLaunchKernelGGL(masked_mm_f32_kernel, grid, dim3(256), 0, stream,
                           a, b, m, o);
    }
}

// Round 20
// 72.169 us; speedup vs baseline: 1.3956x; 1.3956x over previous
//
#include <hip/hip_runtime.h>

// MaskedDenseMatMul: out[b,h,q,k] = (sum_d a[b,h,q,d]*b[b,h,k,d]) * mask[b,0,q,k]
// B=2 H=8 S=2048 D=64, fp32 in/out.  Memory-bound on the 256 MiB output write.
//
// FINAL (R17 configuration, 72.1us measured) — producer/consumer wave
// specialization:
//  - fused prep: A,B fp32->bf16 + mask fp32->u8 (prep at its own BW roofline)
//  - main: each block's 4 waves split into 2 producers (global LOADS only:
//    loop-invariant B frags, depth-4 A+mask staging, MFMA, mask select,
//    ds_write, lgkmcnt(0) + raw s_barrier — no vmcnt drain) and 2 consumers
//    (ZERO global loads: barrier -> ds_read -> nontemporal stores; their
//    vmcnt FIFO holds only stores -> never drained = fill-kernel regime).
//  - double-buffered LDS (16.9KB), 32 barriers/role, natural overlap:
//    producer computes n+1 while consumer stores n.
//  Win ledger: store-last (R8 +15%), long-lived waves/loop-invariant B
//  (R10 +10%), nt+occupancy (R12 +13%), P/C decoupling (R17 +9%).
//  Refuted: burst width, stream contiguity, fetch volume, shallow pipelines,
//  fusion, XCD swizzle, 8 w/SIMD, granule size (R18), storing-wave count (R19).

typedef __attribute__((ext_vector_type(8))) short bf16x8;
typedef __attribute__((ext_vector_type(4))) float f32x4;
typedef __attribute__((ext_vector_type(2))) unsigned int u32x2;

static constexpr int S = 2048;
static constexpr int D = 64;
static constexpr size_t NELEM = (size_t)16 * S * D;   // elems per A/B input
static constexpr size_t NMASK = (size_t)2 * S * S;    // mask elems (B*S*S)
static constexpr int LR = 132;                        // LDS row stride (pad)

__device__ inline short f2bf(float f) {
    union { float f; unsigned u; } v; v.f = f;
    unsigned r = (v.u + 0x7FFFu + ((v.u >> 16) & 1u)) >> 16;
    return (short)r;
}

// ------------- fused pre-pass: cvt A (1024 blk), cvt B (1024), pack mask (4096)
__global__ __launch_bounds__(256) void prep_kernel(const float* __restrict__ a,
                                                   const float* __restrict__ b,
                                                   const float* __restrict__ m,
                                                   short* __restrict__ a16,
                                                   short* __restrict__ b16,
                                                   unsigned char* __restrict__ m8) {
    const int blk = blockIdx.x;
    if (blk < 2048) {
        const float* src = (blk < 1024) ? a : b;
        short* dst       = (blk < 1024) ? a16 : b16;
        size_t i = ((size_t)(blk & 1023) * 256 + threadIdx.x) * 8;
        f32x4 f0 = *(const f32x4*)(src + i);
        f32x4 f1 = *(const f32x4*)(src + i + 4);
        bf16x8 t;
        t[0] = f2bf(f0[0]); t[1] = f2bf(f0[1]); t[2] = f2bf(f0[2]); t[3] = f2bf(f0[3]);
        t[4] = f2bf(f1[0]); t[5] = f2bf(f1[1]); t[6] = f2bf(f1[2]); t[7] = f2bf(f1[3]);
        *(bf16x8*)(dst + i) = t;
    } else {
        size_t i = ((size_t)(blk - 2048) * 256 + threadIdx.x) * 8;
        f32x4 f0 = *(const f32x4*)(m + i);
        f32x4 f1 = *(const f32x4*)(m + i + 4);
        unsigned w0 = 0, w1 = 0;
        w0 |= (f0[0] != 0.f ? 1u : 0u);
        w0 |= (f0[1] != 0.f ? 1u : 0u) << 8;
        w0 |= (f0[2] != 0.f ? 1u : 0u) << 16;
        w0 |= (f0[3] != 0.f ? 1u : 0u) << 24;
        w1 |= (f1[0] != 0.f ? 1u : 0u);
        w1 |= (f1[1] != 0.f ? 1u : 0u) << 8;
        w1 |= (f1[2] != 0.f ? 1u : 0u) << 16;
        w1 |= (f1[3] != 0.f ? 1u : 0u) << 24;
        u32x2 w; w[0] = w0; w[1] = w1;
        *(u32x2*)(m8 + i) = w;
    }
}

// ------------- main kernel: producer/consumer wave specialization ------------
__global__ __launch_bounds__(256, 4) void masked_mm_pc_kernel(
    const short* __restrict__ A16,
    const short* __restrict__ B16,
    const unsigned char* __restrict__ M8,
    float* __restrict__ O) {

    __shared__ float lds[2][16][LR];          // 16896 B double buffer

    const int lane = threadIdx.x & 63;
    const int w    = threadIdx.x >> 6;        // 0,1 producers; 2,3 consumers

    const int gw = blockIdx.x;                // 0..1023
    const int cp = gw & 15;                   // 16 col panels of 128
    const int rq = (gw >> 4) & 3;             // 4 row quarters of 512
    const int bh = gw >> 6;                   // 0..15
    const int bb = bh >> 3;

    const int c0 = cp * 128;
    const int r0 = rq * 512;

    const short* __restrict__ Ab = A16 + (size_t)bh * S * D;
    const short* __restrict__ Bb = B16 + (size_t)bh * S * D;
    const unsigned char* __restrict__ Mb = M8 + (size_t)bb * S * S;
    float* __restrict__ Ob       = O + (size_t)bh * S * S;

    if (w < 2) {
        // ================= PRODUCER (global loads only) =================
        const int rlane = lane & 15;          // MFMA operand row within 16
        const int kg    = lane >> 4;          // k-group 0..3
        const int wc0   = c0 + w * 64;        // this producer's 64 cols

        // loop-invariant B fragments: 4 tiles x (2 x K=32) = 32 VGPR
        bf16x8 bs0[4], bs1[4];
#pragma unroll
        for (int t = 0; t < 4; ++t) {
            const short* pb = Bb + (size_t)(wc0 + t * 16 + rlane) * D + kg * 8;
            bs0[t] = *(const bf16x8*)(pb);
            bs1[t] = *(const bf16x8*)(pb + 32);
        }

        const short*         pa0 = Ab + (size_t)(r0 + rlane) * D + kg * 8;
        const unsigned char* pm0 = Mb + (size_t)(r0 + rlane) * S + wc0 + kg * 4;

        // depth-4 register staging (A frags + mask words) — R12's recipe
        bf16x8   sa0[4], sa1[4];
        unsigned smw[4][4];
#pragma unroll
        for (int n = 0; n < 4; ++n) {
            sa0[n] = *(const bf16x8*)(pa0 + (size_t)n * 16 * D);
            sa1[n] = *(const bf16x8*)(pa0 + (size_t)n * 16 * D + 32);
#pragma unroll
            for (int t = 0; t < 4; ++t)
                smw[n][t] = *(const unsigned*)(pm0 + (size_t)n * 16 * S + t * 16);
        }

#pragma unroll
        for (int n = 0; n < 32; ++n) {
            const int sl = n & 3;

            f32x4 acc[4];
#pragma unroll
            for (int t = 0; t < 4; ++t) {
                f32x4 z = {0.f, 0.f, 0.f, 0.f};
                z = __builtin_amdgcn_mfma_f32_16x16x32_bf16(bs0[t], sa0[sl], z, 0, 0, 0);
                z = __builtin_amdgcn_mfma_f32_16x16x32_bf16(bs1[t], sa1[sl], z, 0, 0, 0);
                acc[t] = z;
            }

            // mask select (producer applies mask so consumer is pure copy)
#pragma unroll
            for (int t = 0; t < 4; ++t) {
                const unsigned m = smw[sl][t];
                acc[t][0] = (m & 0x000000FFu) ? acc[t][0] : 0.f;
                acc[t][1] = (m & 0x0000FF00u) ? acc[t][1] : 0.f;
                acc[t][2] = (m & 0x00FF0000u) ? acc[t][2] : 0.f;
                acc[t][3] = (m & 0xFF000000u) ? acc[t][3] : 0.f;
            }

            // prefetch n+4 (loads only — producer never stores to global)
            if (n + 4 < 32) {
                sa0[sl] = *(const bf16x8*)(pa0 + (size_t)(n + 4) * 16 * D);
                sa1[sl] = *(const bf16x8*)(pa0 + (size_t)(n + 4) * 16 * D + 32);
#pragma unroll
                for (int t = 0; t < 4; ++t)
                    smw[sl][t] = *(const unsigned*)(pm0 + (size_t)(n + 4) * 16 * S + t * 16);
            }

            // publish group n to the double buffer
#pragma unroll
            for (int t = 0; t < 4; ++t)
                *(f32x4*)&lds[n & 1][rlane][w * 64 + t * 16 + kg * 4] = acc[t];

            asm volatile("s_waitcnt lgkmcnt(0)" ::: "memory");
            __builtin_amdgcn_s_barrier();
        }
    } else {
        // ================= CONSUMER (global stores only) =================
        const int cw  = w - 2;                // 0,1 -> rows 0-7 / 8-15
        const int h2  = lane >> 5;            // row within pair
        const int c32 = lane & 31;            // col/4 within 128-col panel

#pragma unroll
        for (int n = 0; n < 32; ++n) {
            __builtin_amdgcn_s_barrier();
            asm volatile("" ::: "memory");    // no ds_read hoist above barrier

#pragma unroll
            for (int p = 0; p < 4; ++p) {
                const int rr = cw * 8 + 2 * p + h2;
                f32x4 v = *(const f32x4*)&lds[n & 1][rr][c32 * 4];
                __builtin_nontemporal_store(v,
                    (f32x4*)(Ob + (size_t)(r0 + n * 16 + rr) * S + c0 + c32 * 4));
            }
        }
    }
}

// ---------------- fallback (ws too small): inline conversion -----------------
__global__ __launch_bounds__(256) void masked_mm_f32_kernel(
    const float* __restrict__ A,
    const float* __restrict__ B,
    const float* __restrict__ M,
    float* __restrict__ O) {

    const int bh   = blockIdx.z;
    const int bb   = bh >> 3;
    const int lane = threadIdx.x & 63;
    const int w    = threadIdx.x >> 6;
    const int r0 = blockIdx.y * 64 + w * 16;
    const int c0 = blockIdx.x * 256;
    const int rlane = lane & 15;
    const int kg    = lane >> 4;

    const float* __restrict__ Ab = A + (size_t)bh * S * D;
    const float* __restrict__ Bb = B + (size_t)bh * S * D;
    const float* __restrict__ Mb = M + (size_t)bb * S * S;
    float* __restrict__ Ob       = O + (size_t)bh * S * S;

    const float* pa = Ab + (size_t)(r0 + rlane) * D + kg * 8;
    f32x4 fa0 = *(const f32x4*)pa, fa1 = *(const f32x4*)(pa + 4);
    f32x4 fa2 = *(const f32x4*)(pa + 32), fa3 = *(const f32x4*)(pa + 36);
    bf16x8 af0, af1;
    af0[0]=f2bf(fa0[0]); af0[1]=f2bf(fa0[1]); af0[2]=f2bf(fa0[2]); af0[3]=f2bf(fa0[3]);
    af0[4]=f2bf(fa1[0]); af0[5]=f2bf(fa1[1]); af0[6]=f2bf(fa1[2]); af0[7]=f2bf(fa1[3]);
    af1[0]=f2bf(fa2[0]); af1[1]=f2bf(fa2[1]); af1[2]=f2bf(fa2[2]); af1[3]=f2bf(fa2[3]);
    af1[4]=f2bf(fa3[0]); af1[5]=f2bf(fa3[1]); af1[6]=f2bf(fa3[2]); af1[7]=f2bf(fa3[3]);

    const size_t rowbase = (size_t)(r0 + rlane) * S + c0;

#pragma unroll
    for (int t = 0; t < 16; ++t) {
        const float* pb = Bb + (size_t)(c0 + t * 16 + rlane) * D + kg * 8;
        f32x4 g0 = *(const f32x4*)pb, g1 = *(const f32x4*)(pb + 4);
        f32x4 g2 = *(const f32x4*)(pb + 32), g3 = *(const f32x4*)(pb + 36);
        bf16x8 b0, b1;
        b0[0]=f2bf(g0[0]); b0[1]=f2bf(g0[1]); b0[2]=f2bf(g0[2]); b0[3]=f2bf(g0[3]);
        b0[4]=f2bf(g1[0]); b0[5]=f2bf(g1[1]); b0[6]=f2bf(g1[2]); b0[7]=f2bf(g1[3]);
        b1[0]=f2bf(g2[0]); b1[1]=f2bf(g2[1]); b1[2]=f2bf(g2[2]); b1[3]=f2bf(g2[3]);
        b1[4]=f2bf(g3[0]); b1[5]=f2bf(g3[1]); b1[6]=f2bf(g3[2]); b1[7]=f2bf(g3[3]);
        f32x4 z = {0.f, 0.f, 0.f, 0.f};
        z = __builtin_amdgcn_mfma_f32_16x16x32_bf16(b0, af0, z, 0, 0, 0);
        z = __builtin_amdgcn_mfma_f32_16x16x32_bf16(b1, af1, z, 0, 0, 0);
        f32x4 mkv = *(const f32x4*)(Mb + rowbase + t * 16 + kg * 4);
        z[0] *= mkv[0]; z[1] *= mkv[1]; z[2] *= mkv[2]; z[3] *= mkv[3];
        *(f32x4*)(Ob + rowbase + t * 16 + kg * 4) = z;
    }
}

extern "C" void kernel_launch(void* const* d_in, const int* in_sizes, int n_in,
                              void* d_out, int out_size, void* d_ws, size_t ws_size,
                              hipStream_t stream) {
    const float* a = (const float*)d_in[0];
    const float* b = (const float*)d_in[1];
    const float* m = (const float*)d_in[2];
    float* o = (float*)d_out;

    dim3 block(256);

    const size_t ws_need = 2 * NELEM * sizeof(short) + NMASK;  // 8.4 + 8.4 MB
    if (ws_size >= ws_need) {
        short* a16 = (short*)d_ws;
        short* b16 = a16 + NELEM;
        unsigned char* m8 = (unsigned char*)(b16 + NELEM);
        hipLaunchKernelGGL(prep_kernel, dim3(6144), block, 0, stream, a, b, m, a16, b16, m8);
        // 1024 blocks = 16 col panels x 4 row quarters x 16 bh
        hipLaunchKernelGGL(masked_mm_pc_kernel, dim3(1024), block, 0, stream,
                           a16, b16, m8, o);
    } else {
        dim3 grid(S / 256, S / 64, 16);
        hipLaunchKernelGGL(masked_mm_f32_kernel, grid, block, 0, stream, a, b, m, o);
    }
}